// Round 5
// baseline (156.790 us; speedup 1.0000x reference)
//
#include <hip/hip_runtime.h>

#define B_ 2
#define C_ 256
#define H_ 56
#define W_ 56
#define N_ 64
#define M_ 8
#define P_ 7
#define Y2_ (H_/2)               // 28 y-row pairs
#define Y4_ (H_/4)               // 14 y-row quads
#define SCTX_ 4                  // column chunks per ctx roi (box roi = whole)
#define JPN_ (1 + (M_)*SCTX_)    // 33 jobs per (b,n) -> 4224 blocks
#define WROW_ 8                  // padded weight-row stride (7 used + col7 = 0)

typedef _Float16 half2v __attribute__((ext_vector_type(2)));

#if __has_builtin(__builtin_amdgcn_fdot2)
#define FDOT2(a, b, c) __builtin_amdgcn_fdot2((a), (b), (c), false)
#else
static __device__ __forceinline__ float FDOT2(half2v a, half2v b, float c) {
    return fmaf((float)a.x, (float)b.x, fmaf((float)a.y, (float)b.y, c));
}
#endif

#if __has_builtin(__builtin_amdgcn_sched_barrier)
#define SCHED_FENCE() __builtin_amdgcn_sched_barrier(0)
#else
#define SCHED_FENCE()
#endif

// ---- workspace layout (dword-element offsets) ----
#define F_FMT4 0
#define N_FMT4 (B_*Y4_*W_*C_*2)              // 802,816 dw  f16 y-QUAD-packed fmap
#define F_OUTS (F_FMT4 + N_FMT4)
#define N_OUTS (B_*N_*49*C_)                 // 1,605,632 staging out [b][n][py][px][c]
#define WS_ELEMS (F_OUTS + N_OUTS)

// prep kernel block ranges (R2-proven: fused transpose + outS zeroing)
#define PREP_T (B_*Y4_*4*2)                  // 224: (b, y4, cgroup, xhalf) transpose
#define PREP_N (PREP_T + 784)                // + zero outS (784*2048 floats)

// ---------------------------------------------------------------------------
// k_prep (R2-verified): two jobs in one dispatch.
//   [0,224):   COALESCED fm -> fmt4 via LDS tile (112B-run reads, 512B/wave
//              c-contiguous packed stores).
//   [224,1008): zero outS
__global__ __launch_bounds__(256) void k_prep(const float* __restrict__ fm,
                                              float* __restrict__ ws_f) {
    __shared__ float t[28 * 257 + 8];        // [x28][y4][c64], x-stride 257 pad
    int bid = blockIdx.x;
    int tid = (int)threadIdx.x;

    if (bid < PREP_T) {                      // ---- y4 pack-transpose ----
        int xh = bid & 1;
        int cg = (bid >> 1) & 3;
        int y4 = (bid >> 3) % Y4_;
        int b  = (bid >> 3) / Y4_;
        int c0 = cg * 64, x0 = xh * 28;
        for (int e = tid; e < 64 * 4 * 28; e += 256) {
            int c_l = e / 112, rem = e % 112;
            int y_l = rem / 28, x_l = rem % 28;
            t[x_l * 257 + y_l * 64 + c_l] =
                fm[(((size_t)b * C_ + c0 + c_l) * H_ + 4 * y4 + y_l) * W_ + x0 + x_l];
        }
        __syncthreads();
        uint2* dst = (uint2*)ws_f;
        for (int e = tid; e < 28 * 64; e += 256) {
            int x_l = e >> 6, c_l = e & 63;
            const float* p = &t[x_l * 257 + c_l];
            half2v lo, hi; uint2 o;
            lo.x = (_Float16)p[0];   lo.y = (_Float16)p[64];
            hi.x = (_Float16)p[128]; hi.y = (_Float16)p[192];
            o.x = __builtin_bit_cast(unsigned int, lo);
            o.y = __builtin_bit_cast(unsigned int, hi);
            dst[(((size_t)b * Y4_ + y4) * W_ + x0 + x_l) * (size_t)C_ + c0 + c_l] = o;
        }
        return;
    }

    {                                        // ---- zero outS ----
        int tz = (bid - PREP_T) * 256 + tid; // < 200,704
        float4 z = {0.0f, 0.0f, 0.0f, 0.0f};
        float4* dst = (float4*)(ws_f + F_OUTS);
        dst[tz * 2]     = z;
        dst[tz * 2 + 1] = z;
    }
}

// ---------------------------------------------------------------------------
// one y-quad's 28 dot2 pairs: weights from two s_wy2 rows (uniform broadcast
// LDS reads), data q0..q3 = the 4 x-columns' packed half2 quads.
static __device__ __forceinline__ void yquad(const unsigned int* wr0,
                                             const unsigned int* wr1,
                                             uint2 q0, uint2 q1, uint2 q2, uint2 q3,
                                             float cs[4][P_]) {
    uint4 wa = *(const uint4*)wr0;
    uint4 wb = *(const uint4*)(wr0 + 4);
    uint4 wc = *(const uint4*)wr1;
    uint4 wd = *(const uint4*)(wr1 + 4);
    half2v w0[7], w1[7];
    w0[0] = __builtin_bit_cast(half2v, wa.x);
    w0[1] = __builtin_bit_cast(half2v, wa.y);
    w0[2] = __builtin_bit_cast(half2v, wa.z);
    w0[3] = __builtin_bit_cast(half2v, wa.w);
    w0[4] = __builtin_bit_cast(half2v, wb.x);
    w0[5] = __builtin_bit_cast(half2v, wb.y);
    w0[6] = __builtin_bit_cast(half2v, wb.z);
    w1[0] = __builtin_bit_cast(half2v, wc.x);
    w1[1] = __builtin_bit_cast(half2v, wc.y);
    w1[2] = __builtin_bit_cast(half2v, wc.z);
    w1[3] = __builtin_bit_cast(half2v, wc.w);
    w1[4] = __builtin_bit_cast(half2v, wd.x);
    w1[5] = __builtin_bit_cast(half2v, wd.y);
    w1[6] = __builtin_bit_cast(half2v, wd.z);
    half2v v0a = __builtin_bit_cast(half2v, q0.x);
    half2v v0b = __builtin_bit_cast(half2v, q0.y);
    half2v v1a = __builtin_bit_cast(half2v, q1.x);
    half2v v1b = __builtin_bit_cast(half2v, q1.y);
    half2v v2a = __builtin_bit_cast(half2v, q2.x);
    half2v v2b = __builtin_bit_cast(half2v, q2.y);
    half2v v3a = __builtin_bit_cast(half2v, q3.x);
    half2v v3b = __builtin_bit_cast(half2v, q3.y);
#pragma unroll
    for (int py = 0; py < P_; ++py) {
        cs[0][py] = FDOT2(w1[py], v0b, FDOT2(w0[py], v0a, cs[0][py]));
        cs[1][py] = FDOT2(w1[py], v1b, FDOT2(w0[py], v1a, cs[1][py]));
        cs[2][py] = FDOT2(w1[py], v2b, FDOT2(w0[py], v2a, cs[2][py]));
        cs[3][py] = FDOT2(w1[py], v3b, FDOT2(w0[py], v3a, cs[3][py]));
    }
}

// ---------------------------------------------------------------------------
// k_main: block = (b, n, j), grid 4224 — R0's proven structure.  CHANGE vs
// R4: the y4 loop is unrolled x2 with a DEPTH-2 prefetch rotation, and the
// prefetch loads are PINNED before the FDOT2 block with sched_barrier(0).
// R4's rotation was silently undone by the compiler (VGPR stayed 56 — the
// scheduler sank the loads back to their uses); the fence makes that
// illegal, so each load has ~2 iterations (~500cy) of compute to land.
// Odd y4-counts are padded by one zero-weight quad (exact: weight rows
// outside the support are 0.0f).  The next x-quad's first 2 row-loads issue
// before the x-stage, covering the inter-quad latency gap.
__global__ __launch_bounds__(256, 4) void k_main(const float* __restrict__ ws_f,
                                                 const float* __restrict__ boxes,
                                                 const float* __restrict__ gt,
                                                 float* __restrict__ outs) {
    __shared__ float        s_wyf[H_][WROW_];      // 1792 B fp32 y staging
    __shared__ unsigned int s_wy2[Y2_ * WROW_];    //  896 B packed half2
    __shared__ float        s_ax[W_][WROW_];       // 1792 B fp32 x-weights

    int bid = blockIdx.x;
    int j   = bid % JPN_;
    int n   = (bid / JPN_) & (N_ - 1);
    int b   = bid / (JPN_ * N_);
    int k, s;
    if (j == 0) { k = 0; s = 0; }
    else        { k = 1 + ((j - 1) >> 2); s = (j - 1) & 3; }
    int tid  = (int)threadIdx.x;
    int c    = tid;

    // ---- roi coords (wave-uniform scalar loads) ----
    const float* bp = boxes + ((size_t)b * N_ + n) * 4;
    float bx1, by1, bx2, by2;
    if (k == 0) {
        bx1 = bp[0]; by1 = bp[1]; bx2 = bp[2]; by2 = bp[3];
    } else {
        const float* gp = gt + ((size_t)b * M_ + (k - 1)) * 4;
        bx1 = fminf(bp[0], gp[0]); by1 = fminf(bp[1], gp[1]);
        bx2 = fmaxf(bp[2], gp[2]); by2 = fmaxf(bp[3], gp[3]);
    }
    float rw = fmaxf(bx2 - bx1, 1.0f);
    float rh = fmaxf(by2 - by1, 1.0f);

    // ---- in-block weight generation (R0 serial column-private form) ----
    for (int e = tid; e < H_ * WROW_; e += 256) ((float*)s_wyf)[e] = 0.0f;
    for (int e = tid; e < W_ * WROW_; e += 256) ((float*)s_ax)[e] = 0.0f;
    __syncthreads();

    if (tid < P_) {                          // y samples, column-private
        int p = tid;
        float bin = rh / 7.0f;
        float gf  = ceilf(bin);
        int   g   = (int)gf;
        float ivg = 1.0f / gf;
        float start = by1 + (float)p * bin;
        for (int ss = 0; ss < g; ++ss) {
            float coord = start + ((float)ss + 0.5f) * bin * ivg;
            if (coord < -1.0f || coord > (float)H_) continue;
            float cc = fmaxf(coord, 0.0f);
            int low = (int)floorf(cc);
            int high; float l;
            if (low >= H_ - 1) { low = H_ - 1; high = H_ - 1; l = 0.0f; }
            else               { high = low + 1; l = cc - (float)low; }
            s_wyf[low][p]  += (1.0f - l) * ivg;
            s_wyf[high][p] += l * ivg;
        }
    } else if (tid >= 64 && tid < 64 + P_) { // x samples, column-private
        int p = tid - 64;
        float bin = rw / 7.0f;
        float gf  = ceilf(bin);
        int   g   = (int)gf;
        float ivg = 1.0f / gf;
        float fs  = (k == 0) ? ivg : ivg * (1.0f / (float)M_);
        float start = bx1 + (float)p * bin;
        for (int ss = 0; ss < g; ++ss) {
            float coord = start + ((float)ss + 0.5f) * bin * ivg;
            if (coord < -1.0f || coord > (float)W_) continue;
            float cc = fmaxf(coord, 0.0f);
            int low = (int)floorf(cc);
            int high; float l;
            if (low >= W_ - 1) { low = W_ - 1; high = W_ - 1; l = 0.0f; }
            else               { high = low + 1; l = cc - (float)low; }
            s_ax[low][p]  += (1.0f - l) * fs;
            s_ax[high][p] += l * fs;
        }
    }
    __syncthreads();

    if (tid < Y2_ * WROW_) {                 // pack y fp32 pairs -> half2
        int q2 = tid >> 3, col = tid & 7;
        half2v h;
        if (col < P_) { h.x = (_Float16)s_wyf[2 * q2][col]; h.y = (_Float16)s_wyf[2 * q2 + 1][col]; }
        else          { h.x = (_Float16)0.0f; h.y = (_Float16)0.0f; }
        s_wy2[tid] = __builtin_bit_cast(unsigned int, h);
    }
    __syncthreads();

    // ---- chunk bounds (uniform per-thread arithmetic, no metadata) ----
    int xlo = min(max((int)floorf(fmaxf(bx1, 0.0f)), 0), W_ - 1);
    int xhi = min(max((int)floorf(bx1 + rw) + 1, 0), W_ - 1) + 1;
    int ylo = min(max((int)floorf(fmaxf(by1, 0.0f)), 0), H_ - 1);
    int yhi = min(max((int)floorf(by1 + rh) + 1, 0), H_ - 1) + 1;
    int xs, xe;
    if (k == 0) { xs = xlo; xe = xhi; }
    else {
        int cw = (xhi - xlo + SCTX_ - 1) >> 2;
        xs = xlo + s * cw;
        xe = min(xs + cw, xhi);
    }
    if (xs >= xe) return;                    // block-uniform, after all barriers

    int ylo4 = ylo >> 2;                     // quad range covering [ylo,yhi)
    int yhi4 = (yhi + 3) >> 2;               // extra rows have zero weight
    if ((yhi4 - ylo4) & 1) {                 // pad to even #quads (zero-weight)
        if (yhi4 < Y4_) yhi4 += 1; else ylo4 -= 1;
    }

    const uint2* f4 = (const uint2*)ws_f + (size_t)b * (Y4_ * W_ * C_);
    const size_t WC = (size_t)W_ * C_;

    float acc[49];
#pragma unroll
    for (int q = 0; q < 49; ++q) acc[q] = 0.0f;
    int live = 0;

    // prologue loads for the first x-quad (rows ylo4, ylo4+1)
    const uint2* cpx = f4 + ((size_t)(ylo4 * W_ + xs)) * C_ + c;
    uint2 a0 = cpx[0], a1 = cpx[C_], a2 = cpx[2 * C_], a3 = cpx[3 * C_];
    const uint2* cpb = cpx + WC;
    uint2 b0 = cpb[0], b1 = cpb[C_], b2 = cpb[2 * C_], b3 = cpb[3 * C_];

    for (int x = xs; x < xe; x += 4) {
        float cs[4][P_];
#pragma unroll
        for (int i = 0; i < 4; ++i)
#pragma unroll
            for (int py = 0; py < P_; ++py) cs[i][py] = 0.0f;

        // x+1..x+3 over-reads past xe/roi edge stay inside d_ws (spill into
        // the outS region at worst); garbage never enters acc (gated on xe).
        const uint2* cp = cpx;
        for (int y4 = ylo4; y4 < yhi4; y4 += 2) {
            // prefetch quads y4+2, y4+3 (tail: clamp = re-read current rows,
            // in-bounds, results simply overwritten next prologue)
            int more = (y4 + 2 < yhi4);
            const uint2* cq = cp + (more ? 2 * WC : 0);
            uint2 e0 = cq[0], e1 = cq[C_], e2 = cq[2 * C_], e3 = cq[3 * C_];
            const uint2* cr = cq + (more ? WC : 0);
            uint2 f0 = cr[0], f1 = cr[C_], f2 = cr[2 * C_], f3 = cr[3 * C_];
            SCHED_FENCE();                   // loads stay ABOVE the math

            yquad(&s_wy2[(2 * y4) * WROW_],     &s_wy2[(2 * y4 + 1) * WROW_],
                  a0, a1, a2, a3, cs);
            yquad(&s_wy2[(2 * y4 + 2) * WROW_], &s_wy2[(2 * y4 + 3) * WROW_],
                  b0, b1, b2, b3, cs);

            a0 = e0; a1 = e1; a2 = e2; a3 = e3;
            b0 = f0; b1 = f1; b2 = f2; b3 = f3;
            cp += 2 * WC;
        }

        // issue next x-quad's prologue BEFORE the x-stage (covers the gap)
        cpx += (x + 4 < xe) ? 4 * (size_t)C_ : 0;   // tail: clamp, in-bounds
        a0 = cpx[0]; a1 = cpx[C_]; a2 = cpx[2 * C_]; a3 = cpx[3 * C_];
        const uint2* nb = cpx + WC;
        b0 = nb[0]; b1 = nb[C_]; b2 = nb[2 * C_]; b3 = nb[3 * C_];
        SCHED_FENCE();

        // ---- x-stage (fp32, exact weights from LDS) ----
#pragma unroll
        for (int i = 0; i < 4; ++i) {
            if (x + i < xe) {                         // wave-uniform branch
                float av[8];
                *(float4*)(&av[0]) = *(const float4*)&s_ax[x + i][0];
                *(float4*)(&av[4]) = *(const float4*)&s_ax[x + i][4];
#pragma unroll
                for (int px = 0; px < P_; ++px) {
                    float w = av[px];
                    if (w != 0.0f) {
                        live |= 1 << px;
#pragma unroll
                        for (int py = 0; py < P_; ++py)
                            acc[py * P_ + px] = fmaf(w, cs[i][py], acc[py * P_ + px]);
                    }
                }
            }
        }
    }

    // ---- epilogue: live-px coalesced wave-atomics into outS ----
    float* os = outs + ((size_t)b * N_ + n) * (49 * C_) + c;
#pragma unroll
    for (int px = 0; px < P_; ++px) {
        if (live & (1 << px)) {
#pragma unroll
            for (int py = 0; py < P_; ++py)
                atomicAdd(os + (py * P_ + px) * C_, acc[py * P_ + px]);
        }
    }
}

// ---------------------------------------------------------------------------
// k_final: outS [b][n][py][px][c] -> out [b][n][c][py][px] via padded LDS.
// 512 blocks: (bn, 64-channel group) tiles (R1-verified).
__global__ __launch_bounds__(256) void k_final(const float* __restrict__ outs,
                                               float* __restrict__ out) {
    __shared__ float t[49 * 65];             // pad 65: conflict-free transpose
    int bid = blockIdx.x;                    // bn*4 + cg
    int cg  = bid & 3;
    int bn  = bid >> 2;
    int tid = (int)threadIdx.x;
    const float* src = outs + (size_t)bn * (49 * C_) + cg * 64;
    for (int e = tid; e < 49 * 64; e += 256) {
        int q = e >> 6, c = e & 63;
        t[q * 65 + c] = src[q * C_ + c];     // coalesced read
    }
    __syncthreads();
    float* dst = out + (size_t)bn * (C_ * 49) + (size_t)cg * 64 * 49;
    for (int e = tid; e < 64 * 49; e += 256) {
        int c = e / 49, q = e - c * 49;
        dst[e] = t[q * 65 + c];              // coalesced write
    }
}

// ---------------------------------------------------------------------------
extern "C" void kernel_launch(void* const* d_in, const int* in_sizes, int n_in,
                              void* d_out, int out_size, void* d_ws, size_t ws_size,
                              hipStream_t stream) {
    const float* fm    = (const float*)d_in[0];
    const float* boxes = (const float*)d_in[1];
    const float* gt    = (const float*)d_in[2];
    float* ws_f = (float*)d_ws;
    float* out  = (float*)d_out;
    float* outs = ws_f + F_OUTS;

    k_prep<<<PREP_N, 256, 0, stream>>>(fm, ws_f);
    k_main<<<B_ * N_ * JPN_, 256, 0, stream>>>(ws_f, boxes, gt, outs);
    k_final<<<B_ * N_ * 4, 256, 0, stream>>>(outs, out);
}